// Round 3
// baseline (109.104 us; speedup 1.0000x reference)
//
#include <hip/hip_runtime.h>

// GenomeNet: B=4096, N_IN=W=N_OUT=1024, L=8 hidden, D=16 fan-in.
// R9: R7 structure (TB=16, lane-pair-split 32B rows, 8-deep ds_read
// pipeline, plain fmaf inner loop — R8's inline-asm fma_mix REVERTED:
// it left VALU busy-cycles unchanged and cost +15% via worse scheduling)
// + one-pass-ahead software pipeline of the (src,w) weight fetch.
//   R7 residual: every pass opened with 8 L2 loads feeding the ds_read
//   addresses; all 16 waves/CU issue them post-barrier simultaneously
//   (~128 KB/CU at ~56 B/cyc => ~2k cyc bubble/layer with no coverable
//   work). Prefetching into a second register set issues them one full
//   compute-pass + barrier ahead of use.

#define TB       16
#define W_NODES  1024
#define LAYERS   8
#define ROW_H    16                    // halfs per node row (32 B)
#define BUF_H    (W_NODES * ROW_H)     // 16384 halfs = 32 KB

typedef _Float16 h8 __attribute__((ext_vector_type(8)));

__device__ __forceinline__ float fast_tanh(float x) {
    // tanh(x) = 1 - 2/(e^{2x}+1)
    float a = __builtin_amdgcn_exp2f(x * 2.8853900817779268f);
    return 1.0f - 2.0f * __builtin_amdgcn_rcpf(a + 1.0f);
}

// Per-node edge data: 16 src indices + 16 weights, kept packed in regs.
struct SW { int4 s[4]; float4 w[4]; };

__device__ __forceinline__ void load_sw(const int4* __restrict__ sp,
                                        const float4* __restrict__ wp,
                                        SW& d) {
    #pragma unroll
    for (int q = 0; q < 4; ++q) { d.s[q] = sp[q]; d.w[q] = wp[q]; }
}

// Gather 16 half-rows (16 B each) for one node with a software pipeline.
// hfo = half-offset in halfs (0 or 8). Accumulates this thread's 8 batches.
__device__ __forceinline__ void gather16_half(const _Float16* __restrict__ rd,
                                              const SW& d,
                                              const int hfo,
                                              float* __restrict__ acc)
{
    int si[16]; float wi[16];
    #pragma unroll
    for (int q = 0; q < 4; ++q) {
        si[4*q+0] = d.s[q].x; si[4*q+1] = d.s[q].y;
        si[4*q+2] = d.s[q].z; si[4*q+3] = d.s[q].w;
        wi[4*q+0] = d.w[q].x; wi[4*q+1] = d.w[q].y;
        wi[4*q+2] = d.w[q].z; wi[4*q+3] = d.w[q].w;
    }

#define LDV(i) (*(const h8*)(rd + ((si[i] << 4) + hfo)))
#define FMA8(g, w)                                        \
    do {                                                  \
        const float _w = (w);                             \
        _Pragma("unroll")                                 \
        for (int j = 0; j < 8; ++j)                       \
            acc[j] = fmaf((float)(g)[j], _w, acc[j]);     \
    } while (0)

    h8 g0 = LDV(0);  h8 g1 = LDV(1);  h8 g2 = LDV(2);  h8 g3 = LDV(3);
    h8 g4 = LDV(4);  h8 g5 = LDV(5);  h8 g6 = LDV(6);  h8 g7 = LDV(7);

    FMA8(g0, wi[0]);  FMA8(g1, wi[1]);
    g0 = LDV(8);      g1 = LDV(9);
    FMA8(g2, wi[2]);  FMA8(g3, wi[3]);
    g2 = LDV(10);     g3 = LDV(11);
    FMA8(g4, wi[4]);  FMA8(g5, wi[5]);
    g4 = LDV(12);     g5 = LDV(13);
    FMA8(g6, wi[6]);  FMA8(g7, wi[7]);
    g6 = LDV(14);     g7 = LDV(15);

    FMA8(g0, wi[8]);  FMA8(g1, wi[9]);
    FMA8(g2, wi[10]); FMA8(g3, wi[11]);
    FMA8(g4, wi[12]); FMA8(g5, wi[13]);
    FMA8(g6, wi[14]); FMA8(g7, wi[15]);
#undef LDV
#undef FMA8
}

// Hidden pass: gather + tanh + fp16 half-row write.
__device__ __forceinline__ void pass_hidden(const _Float16* __restrict__ rd,
                                            _Float16* __restrict__ wr,
                                            const int n, const int hfo,
                                            const SW& d) {
    float acc[8];
    #pragma unroll
    for (int j = 0; j < 8; ++j) acc[j] = 0.0f;
    gather16_half(rd, d, hfo, acc);
    h8 hv;
    #pragma unroll
    for (int j = 0; j < 8; ++j) hv[j] = (_Float16)fast_tanh(acc[j]);
    *(h8*)(wr + n * ROW_H + hfo) = hv;     // 8 lanes/quad-group: clean
}

// Output pass: gather + identity + coalesced fp32 global stores.
__device__ __forceinline__ void pass_out(const _Float16* __restrict__ rd,
                                         float* __restrict__ out,
                                         const int bb, const int n,
                                         const int hfo, const SW& d) {
    float acc[8];
    #pragma unroll
    for (int j = 0; j < 8; ++j) acc[j] = 0.0f;
    gather16_half(rd, d, hfo, acc);
    #pragma unroll
    for (int j = 0; j < 8; ++j)
        out[(size_t)(bb + j) * W_NODES + n] = acc[j];
}

__global__ __launch_bounds__(1024, 4) void genome_net(
    const float* __restrict__ x,
    const int*   __restrict__ src_hidden,
    const float* __restrict__ w_hidden,
    const int*   __restrict__ src_out,
    const float* __restrict__ w_out,
    float*       __restrict__ out)
{
    extern __shared__ _Float16 lds[];
    _Float16* bufA = lds;              // [1024 nodes][16 batch] fp16, 32 KB
    _Float16* bufB = lds + BUF_H;

    const int t   = threadIdx.x;
    const int pr  = t >> 1;            // pair index 0..511
    const int hf  = t & 1;             // which 16 B half of the row
    const int hfo = hf << 3;           // half offset in halfs
    const int b0  = blockIdx.x * TB;
    const int bb  = b0 + hfo;          // this thread's 8-batch base

    const int n0 = pr;                 // pass-0 node
    const int n1 = 512 + pr;           // pass-1 node

    const int4*   shp = (const int4*)src_hidden;
    const float4* whp = (const float4*)w_hidden;
    const int4*   sop = (const int4*)src_out;
    const float4* wop = (const float4*)w_out;

    // ---- Prefetch layer-0 weights for both passes (in flight under the
    // x-staging loads + barrier).
    SW A, B;
    load_sw(shp + (n0 << 2), whp + (n0 << 2), A);
    load_sw(shp + (n1 << 2), whp + (n1 << 2), B);

    // ---- Stage x: fp32 -> fp16 half-rows, 2 node passes. Coalesced.
    #pragma unroll
    for (int p = 0; p < 2; ++p) {
        const int n = (p << 9) + pr;
        h8 hv;
        #pragma unroll
        for (int j = 0; j < 8; ++j)
            hv[j] = (_Float16)x[(size_t)(bb + j) * W_NODES + n];
        *(h8*)(bufA + n * ROW_H + hfo) = hv;   // 8 lanes/quad-group: clean
    }
    __syncthreads();

    _Float16* rd = bufA;
    _Float16* wr = bufB;

    #pragma unroll 1
    for (int l = 0; l < LAYERS; ++l) {
        const bool last = (l == LAYERS - 1);
        // next-pass weight row pointers (output rows when leaving layer 7);
        // wave-uniform select, issued one compute-pass ahead of use.
        const int  rn0 = ((l + 1) << 10) + n0;
        const int  rn1 = ((l + 1) << 10) + n1;
        const int4*   spA = last ? sop + (n0 << 2) : shp + (rn0 << 2);
        const float4* wpA = last ? wop + (n0 << 2) : whp + (rn0 << 2);
        const int4*   spB = last ? sop + (n1 << 2) : shp + (rn1 << 2);
        const float4* wpB = last ? wop + (n1 << 2) : whp + (rn1 << 2);

        pass_hidden(rd, wr, n0, hfo, A);   // consumes A
        load_sw(spA, wpA, A);              // prefetch next pass-0 set

        pass_hidden(rd, wr, n1, hfo, B);   // consumes B
        load_sw(spB, wpB, B);              // prefetch next pass-1 set

        __syncthreads();
        _Float16* tmp = rd; rd = wr; wr = tmp;
    }

    // ---- Output layer: identity activation, fp32 accumulate + stores.
    pass_out(rd, out, bb, n0, hfo, A);
    pass_out(rd, out, bb, n1, hfo, B);
}

extern "C" void kernel_launch(void* const* d_in, const int* in_sizes, int n_in,
                              void* d_out, int out_size, void* d_ws, size_t ws_size,
                              hipStream_t stream) {
    const float* x  = (const float*)d_in[0];
    const int*   sh = (const int*)  d_in[1];
    const float* wh = (const float*)d_in[2];
    const int*   so = (const int*)  d_in[3];
    const float* wo = (const float*)d_in[4];
    float* out = (float*)d_out;

    const int shmem = 2 * BUF_H * (int)sizeof(_Float16);   // 65536 B
    hipFuncSetAttribute(reinterpret_cast<const void*>(genome_net),
                        hipFuncAttributeMaxDynamicSharedMemorySize, shmem);

    genome_net<<<dim3(4096 / TB), dim3(1024), shmem, stream>>>(
        x, sh, wh, so, wo, out);
}